// Round 2
// baseline (262.330 us; speedup 1.0000x reference)
//
#include <hip/hip_runtime.h>
#include <stdint.h>

#define CCH 64
#define HWPIX 65536
#define NBINS 256
#define TPX 128   // pixels per main-kernel block

// ws layout (float slots):
// [0    .. 1023] : dominant bins, int32, B*C entries
// [1024 .. 5119] : WcolT[o*64+c] = W1[o*64+c] * inv1[o]   (row-major over o)
// [5120 .. 5183] : base_pre[o]
// [5184 .. 5247] : w2[o]
// [5248 .. 5251] : scalars {inv2, beta2p, b2, s_empty}
// [5312 .. 5375] : s1[c] = sigmoid for single-hit mask {c}

__global__ __launch_bounds__(64) void precomp_kernel(
    const float* __restrict__ w1, const float* __restrict__ b1,
    const float* __restrict__ g1, const float* __restrict__ be1,
    const float* __restrict__ m1, const float* __restrict__ v1,
    const float* __restrict__ w2, const float* __restrict__ b2,
    const float* __restrict__ g2, const float* __restrict__ be2,
    const float* __restrict__ m2, const float* __restrict__ v2,
    float* __restrict__ ws)
{
    int o = threadIdx.x;  // 0..63
    float inv1 = g1[o] * rsqrtf(v1[o] + 1e-5f);
    float S = 0.f;
    for (int c = 0; c < CCH; ++c) S += w1[o * CCH + c];
    float beta1p = be1[o] - m1[o] * inv1;
    float base_pre = (S + b1[o]) * inv1 + beta1p;
    for (int c = 0; c < CCH; ++c) ws[1024 + o * CCH + c] = w1[o * CCH + c] * inv1;
    ws[5120 + o] = base_pre;
    float w2o = w2[o];
    ws[5184 + o] = w2o;
    // t_base = sum_o relu(base_pre)*w2 across the single wave
    float t = fmaxf(base_pre, 0.f) * w2o;
    #pragma unroll
    for (int off = 32; off > 0; off >>= 1) t += __shfl_down(t, off, 64);
    if (o == 0) {
        float inv2 = g2[0] * rsqrtf(v2[0] + 1e-5f);
        float beta2p = be2[0] - m2[0] * inv2;
        float z = (t + b2[0]) * inv2 + beta2p;
        ws[5248] = inv2;
        ws[5249] = beta2p;
        ws[5250] = b2[0];
        ws[5251] = 1.f / (1.f + expf(-z));
    }
    __syncthreads();   // makes ws[5248..5250] + tables visible block-wide
    // s1 table: sigmoid when exactly channel c hits its dominant bin
    {
        int c = o;
        float t1 = 0.f;
        for (int oo = 0; oo < CCH; ++oo) {
            float acc = ws[5120 + oo] - ws[1024 + oo * CCH + c];
            t1 += fmaxf(acc, 0.f) * ws[5184 + oo];
        }
        float z = (t1 + ws[5250]) * ws[5248] + ws[5249];
        ws[5312 + c] = 1.f / (1.f + expf(-z));
    }
}

// One block per (b,c) image: 256-bin histogram + first-max argmax.
// 16 sub-histograms (16 lanes each), +1 padded to stagger banks.
__global__ __launch_bounds__(256) void hist_kernel(
    const float* __restrict__ x, int* __restrict__ dom)
{
    __shared__ unsigned h[16][NBINS + 1];
    __shared__ unsigned long long red[NBINS];
    int tid = threadIdx.x;
    const float4* xp = (const float4*)(x + (size_t)blockIdx.x * HWPIX);

    for (int i = tid; i < 16 * (NBINS + 1); i += 256) ((unsigned*)h)[i] = 0;
    __syncthreads();

    unsigned* hmine = h[tid >> 4];
    const float scale = 256.0f / 255.0f;   // same f32 value JAX uses
    #pragma unroll 4
    for (int t = 0; t < HWPIX / 4 / 256; ++t) {
        float4 v = xp[t * 256 + tid];
        float vv[4] = {v.x, v.y, v.z, v.w};
        #pragma unroll
        for (int j = 0; j < 4; ++j) {
            float f = vv[j];
            if (f >= 0.f && f <= 255.f) {       // histc ignores out-of-range
                int bi = (int)(f * scale);      // trunc == JAX astype(int32), f>=0
                bi = bi > NBINS - 1 ? NBINS - 1 : bi;
                atomicAdd(&hmine[bi], 1u);
            }
        }
    }
    __syncthreads();

    unsigned cnt = 0;
    #pragma unroll
    for (int k = 0; k < 16; ++k) cnt += h[k][tid];
    // pack so max(key) == (max count, smallest bin index) -> jnp.argmax tie rule
    red[tid] = ((unsigned long long)cnt << 32) | (unsigned)(NBINS - 1 - tid);
    __syncthreads();
    #pragma unroll
    for (int s = 128; s > 0; s >>= 1) {
        if (tid < s) {
            unsigned long long a = red[tid], b = red[tid + s];
            red[tid] = a > b ? a : b;
        }
        __syncthreads();
    }
    if (tid == 0) dom[blockIdx.x] = (NBINS - 1) - (int)(red[0] & 0xffffffffu);
}

// Tile 64ch x 128px into LDS with float4 traffic; per-pixel mask + sigmoid.
__global__ __launch_bounds__(256) void main_kernel(
    const float* __restrict__ x, const float* __restrict__ ws,
    const int* __restrict__ dom, float* __restrict__ out)
{
    __shared__ float tile[CCH * TPX];    // 32 KiB, [c][p]
    __shared__ float Wrow[CCH * CCH];    // 16 KiB
    __shared__ float ss[TPX];
    __shared__ float bp_s[CCH];
    __shared__ float w2_s[CCH];
    __shared__ float s1_s[CCH];
    __shared__ int   dom_s[CCH];
    __shared__ float sc[4];

    int tid = threadIdx.x;
    int b = blockIdx.x >> 9;                 // 512 blocks per batch image
    int p0 = (blockIdx.x & 511) * TPX;       // pixel base within image

    for (int i = tid; i < CCH * CCH; i += 256) Wrow[i] = ws[1024 + i];
    if (tid < CCH) {
        bp_s[tid]  = ws[5120 + tid];
        w2_s[tid]  = ws[5184 + tid];
        s1_s[tid]  = ws[5312 + tid];
        dom_s[tid] = dom[b * CCH + tid];
    }
    if (tid < 4) sc[tid] = ws[5248 + tid];

    const float4* xb4 = (const float4*)(x + ((size_t)b << 22));
    float4* tile4 = (float4*)tile;
    int p04 = p0 >> 2;
    #pragma unroll
    for (int k = 0; k < (CCH * TPX / 4) / 256; ++k) {    // 8 iterations
        int id = k * 256 + tid;
        int c = id >> 5, col = id & 31;                   // 32 float4 per channel
        tile4[id] = xb4[((size_t)c << 14) + p04 + col];
    }
    __syncthreads();

    if (tid < TPX) {
        unsigned long long m = 0ull;
        #pragma unroll
        for (int c = 0; c < CCH; ++c) {
            float v = tile[c * TPX + tid];
            m |= (unsigned long long)((int)floorf(v) == dom_s[c]) << c;
        }
        float s;
        if (m == 0ull) {
            s = sc[3];
        } else if ((m & (m - 1)) == 0ull) {
            s = s1_s[__builtin_ctzll(m)];
        } else {
            float t = 0.f;
            for (int o = 0; o < CCH; ++o) {
                float acc = bp_s[o];
                unsigned long long mm = m;
                const float* row = &Wrow[o << 6];
                while (mm) {
                    int c = __builtin_ctzll(mm);
                    mm &= mm - 1;
                    acc -= row[c];
                }
                t += fmaxf(acc, 0.f) * w2_s[o];
            }
            float z = (t + sc[2]) * sc[0] + sc[1];
            s = 1.f / (1.f + expf(-z));
        }
        ss[tid] = s;
    }
    __syncthreads();

    float4* ob4 = (float4*)(out + ((size_t)b << 22));
    #pragma unroll
    for (int k = 0; k < (CCH * TPX / 4) / 256; ++k) {    // 8 iterations
        int id = k * 256 + tid;
        int c = id >> 5, col = id & 31;
        float4 v = tile4[id];
        const float4 sv = *(const float4*)&ss[col << 2];
        v.x *= sv.x; v.y *= sv.y; v.z *= sv.z; v.w *= sv.w;
        ob4[((size_t)c << 14) + p04 + col] = v;
    }
}

extern "C" void kernel_launch(void* const* d_in, const int* in_sizes, int n_in,
                              void* d_out, int out_size, void* d_ws, size_t ws_size,
                              hipStream_t stream) {
    const float* x   = (const float*)d_in[0];
    const float* w1  = (const float*)d_in[1];
    const float* b1  = (const float*)d_in[2];
    const float* g1  = (const float*)d_in[3];
    const float* be1 = (const float*)d_in[4];
    const float* m1  = (const float*)d_in[5];
    const float* v1  = (const float*)d_in[6];
    const float* w2  = (const float*)d_in[7];
    const float* b2  = (const float*)d_in[8];
    const float* g2  = (const float*)d_in[9];
    const float* be2 = (const float*)d_in[10];
    const float* m2  = (const float*)d_in[11];
    const float* v2  = (const float*)d_in[12];

    float* ws  = (float*)d_ws;
    int*   dom = (int*)d_ws;                 // aliases ws[0..1023]
    float* outp = (float*)d_out;

    int B = in_sizes[0] / (CCH * HWPIX);     // 16

    precomp_kernel<<<1, 64, 0, stream>>>(w1, b1, g1, be1, m1, v1,
                                         w2, b2, g2, be2, m2, v2, ws);
    hist_kernel<<<B * CCH, 256, 0, stream>>>(x, dom);
    main_kernel<<<B * (HWPIX / TPX), 256, 0, stream>>>(x, ws, dom, outp);
}

// Round 3
// 193.060 us; speedup vs baseline: 1.3588x; 1.3588x over previous
//
#include <hip/hip_runtime.h>
#include <stdint.h>

#define CCH 64
#define HWPIX 65536
#define NBINS 256

// ws layout (float slots):
// [0    .. 1023] : dominant bins, int32, B*C entries
// [1024 .. 5119] : WcolT[o*64+c] = W1[o*64+c] * inv1[o]   (row-major over o)
// [5120 .. 5183] : base_pre[o]
// [5184 .. 5247] : w2[o]
// [5248 .. 5251] : scalars {inv2, beta2p, b2, s_empty}
// [5312 .. 5375] : s1[c] = sigmoid for single-hit mask {c}

__global__ __launch_bounds__(64) void precomp_kernel(
    const float* __restrict__ w1, const float* __restrict__ b1,
    const float* __restrict__ g1, const float* __restrict__ be1,
    const float* __restrict__ m1, const float* __restrict__ v1,
    const float* __restrict__ w2, const float* __restrict__ b2,
    const float* __restrict__ g2, const float* __restrict__ be2,
    const float* __restrict__ m2, const float* __restrict__ v2,
    float* __restrict__ ws)
{
    int o = threadIdx.x;  // 0..63
    float inv1 = g1[o] * rsqrtf(v1[o] + 1e-5f);
    float S = 0.f;
    for (int c = 0; c < CCH; ++c) S += w1[o * CCH + c];
    float beta1p = be1[o] - m1[o] * inv1;
    float base_pre = (S + b1[o]) * inv1 + beta1p;
    for (int c = 0; c < CCH; ++c) ws[1024 + o * CCH + c] = w1[o * CCH + c] * inv1;
    ws[5120 + o] = base_pre;
    float w2o = w2[o];
    ws[5184 + o] = w2o;
    float t = fmaxf(base_pre, 0.f) * w2o;
    #pragma unroll
    for (int off = 32; off > 0; off >>= 1) t += __shfl_down(t, off, 64);
    if (o == 0) {
        float inv2 = g2[0] * rsqrtf(v2[0] + 1e-5f);
        float beta2p = be2[0] - m2[0] * inv2;
        float z = (t + b2[0]) * inv2 + beta2p;
        ws[5248] = inv2;
        ws[5249] = beta2p;
        ws[5250] = b2[0];
        ws[5251] = 1.f / (1.f + expf(-z));
    }
    __syncthreads();
    // s1 table: sigmoid when exactly channel c hits its dominant bin
    {
        int c = o;
        float t1 = 0.f;
        for (int oo = 0; oo < CCH; ++oo) {
            float acc = ws[5120 + oo] - ws[1024 + oo * CCH + c];
            t1 += fmaxf(acc, 0.f) * ws[5184 + oo];
        }
        float z = (t1 + ws[5250]) * ws[5248] + ws[5249];
        ws[5312 + c] = 1.f / (1.f + expf(-z));
    }
}

// One block per (b,c) image: 256-bin histogram + first-max argmax.
__global__ __launch_bounds__(256) void hist_kernel(
    const float* __restrict__ x, int* __restrict__ dom)
{
    __shared__ unsigned h[16][NBINS + 1];
    __shared__ unsigned long long red[NBINS];
    int tid = threadIdx.x;
    const float4* xp = (const float4*)(x + (size_t)blockIdx.x * HWPIX);

    for (int i = tid; i < 16 * (NBINS + 1); i += 256) ((unsigned*)h)[i] = 0;
    __syncthreads();

    unsigned* hmine = h[tid >> 4];
    const float scale = 256.0f / 255.0f;
    #pragma unroll 4
    for (int t = 0; t < HWPIX / 4 / 256; ++t) {
        float4 v = xp[t * 256 + tid];
        float vv[4] = {v.x, v.y, v.z, v.w};
        #pragma unroll
        for (int j = 0; j < 4; ++j) {
            float f = vv[j];
            if (f >= 0.f && f <= 255.f) {
                int bi = (int)(f * scale);
                bi = bi > NBINS - 1 ? NBINS - 1 : bi;
                atomicAdd(&hmine[bi], 1u);
            }
        }
    }
    __syncthreads();

    unsigned cnt = 0;
    #pragma unroll
    for (int k = 0; k < 16; ++k) cnt += h[k][tid];
    red[tid] = ((unsigned long long)cnt << 32) | (unsigned)(NBINS - 1 - tid);
    __syncthreads();
    #pragma unroll
    for (int s = 128; s > 0; s >>= 1) {
        if (tid < s) {
            unsigned long long a = red[tid], b = red[tid + s];
            red[tid] = a > b ? a : b;
        }
        __syncthreads();
    }
    if (tid == 0) dom[blockIdx.x] = (NBINS - 1) - (int)(red[0] & 0xffffffffu);
}

// Thread-per-pixel: 64 coalesced channel loads in registers, mask via float
// range compare, rare-path tables read from global (L1/L2 resident),
// non-temporal output stores (don't evict x from LLC).
__global__ __launch_bounds__(256) void main_kernel(
    const float* __restrict__ x, const float* __restrict__ ws,
    const int* __restrict__ dom, float* __restrict__ out)
{
    __shared__ float df[CCH];      // dominant bin as float
    __shared__ float s1_s[CCH];
    __shared__ float sc4[4];

    int tid = threadIdx.x;
    int b = blockIdx.x >> 8;                  // 256 blocks per batch image
    int hw = ((blockIdx.x & 255) << 8) | tid; // pixel within image

    if (tid < CCH) {
        df[tid]   = (float)dom[b * CCH + tid];
        s1_s[tid] = ws[5312 + tid];
    }
    if (tid < 4) sc4[tid] = ws[5248 + tid];
    __syncthreads();

    const float* xb = x + ((size_t)b << 22);  // b * 64 * 65536
    float vx[CCH];
    #pragma unroll
    for (int c = 0; c < CCH; ++c) vx[c] = xb[((size_t)c << 16) + hw];

    unsigned long long m = 0ull;
    #pragma unroll
    for (int c = 0; c < CCH; ++c) {
        float d = df[c];
        // floor(v)==d  <=>  d <= v < d+1  (d integer, v >= 0)
        m |= (unsigned long long)(vx[c] >= d && vx[c] < d + 1.0f) << c;
    }

    float s;
    if (m == 0ull) {
        s = sc4[3];
    } else if ((m & (m - 1)) == 0ull) {
        s = s1_s[__builtin_ctzll(m)];
    } else {
        float t = 0.f;
        for (int o = 0; o < CCH; ++o) {
            float acc = ws[5120 + o];
            unsigned long long mm = m;
            const float* row = ws + 1024 + (o << 6);
            while (mm) {
                int c = __builtin_ctzll(mm);
                mm &= mm - 1;
                acc -= row[c];
            }
            t += fmaxf(acc, 0.f) * ws[5184 + o];
        }
        float z = (t + sc4[2]) * sc4[0] + sc4[1];
        s = 1.f / (1.f + expf(-z));
    }

    float* ob = out + ((size_t)b << 22);
    #pragma unroll
    for (int c = 0; c < CCH; ++c)
        __builtin_nontemporal_store(vx[c] * s, &ob[((size_t)c << 16) + hw]);
}

extern "C" void kernel_launch(void* const* d_in, const int* in_sizes, int n_in,
                              void* d_out, int out_size, void* d_ws, size_t ws_size,
                              hipStream_t stream) {
    const float* x   = (const float*)d_in[0];
    const float* w1  = (const float*)d_in[1];
    const float* b1  = (const float*)d_in[2];
    const float* g1  = (const float*)d_in[3];
    const float* be1 = (const float*)d_in[4];
    const float* m1  = (const float*)d_in[5];
    const float* v1  = (const float*)d_in[6];
    const float* w2  = (const float*)d_in[7];
    const float* b2  = (const float*)d_in[8];
    const float* g2  = (const float*)d_in[9];
    const float* be2 = (const float*)d_in[10];
    const float* m2  = (const float*)d_in[11];
    const float* v2  = (const float*)d_in[12];

    float* ws  = (float*)d_ws;
    int*   dom = (int*)d_ws;                 // aliases ws[0..1023]
    float* outp = (float*)d_out;

    int B = in_sizes[0] / (CCH * HWPIX);     // 16

    precomp_kernel<<<1, 64, 0, stream>>>(w1, b1, g1, be1, m1, v1,
                                         w2, b2, g2, be2, m2, v2, ws);
    hist_kernel<<<B * CCH, 256, 0, stream>>>(x, dom);
    main_kernel<<<B * (HWPIX / 256), 256, 0, stream>>>(x, ws, dom, outp);
}

// Round 4
// 167.947 us; speedup vs baseline: 1.5620x; 1.1495x over previous
//
#include <hip/hip_runtime.h>
#include <stdint.h>

#define CCH 64
#define HWPIX 65536
#define NBINS 256

typedef float f4 __attribute__((ext_vector_type(4)));

// ws layout (float slots):
// [0    .. 1023] : dominant bins, int32, B*C entries
// [1024 .. 5119] : WcolT[o*64+c] = W1[o*64+c] * inv1[o]
// [5120 .. 5183] : base_pre[o]
// [5184 .. 5247] : w2[o]
// [5248 .. 5251] : scalars {inv2, beta2p, b2, s_empty}
// [5312 .. 5375] : s1[c]  = sigmoid for single-hit mask {c}
// [8192 ..12287] : s2[c1*64+c2] = sigmoid for two-hit mask {c1,c2}

__global__ __launch_bounds__(64) void precomp_kernel(
    const float* __restrict__ w1, const float* __restrict__ b1,
    const float* __restrict__ g1, const float* __restrict__ be1,
    const float* __restrict__ m1, const float* __restrict__ v1,
    const float* __restrict__ w2, const float* __restrict__ b2,
    const float* __restrict__ g2, const float* __restrict__ be2,
    const float* __restrict__ m2, const float* __restrict__ v2,
    float* __restrict__ ws)
{
    int o = threadIdx.x;  // 0..63
    float inv1 = g1[o] * rsqrtf(v1[o] + 1e-5f);
    float S = 0.f;
    for (int c = 0; c < CCH; ++c) S += w1[o * CCH + c];
    float beta1p = be1[o] - m1[o] * inv1;
    float base_pre = (S + b1[o]) * inv1 + beta1p;
    for (int c = 0; c < CCH; ++c) ws[1024 + o * CCH + c] = w1[o * CCH + c] * inv1;
    ws[5120 + o] = base_pre;
    float w2o = w2[o];
    ws[5184 + o] = w2o;
    float t = fmaxf(base_pre, 0.f) * w2o;
    #pragma unroll
    for (int off = 32; off > 0; off >>= 1) t += __shfl_down(t, off, 64);
    if (o == 0) {
        float inv2 = g2[0] * rsqrtf(v2[0] + 1e-5f);
        float beta2p = be2[0] - m2[0] * inv2;
        float z = (t + b2[0]) * inv2 + beta2p;
        ws[5248] = inv2;
        ws[5249] = beta2p;
        ws[5250] = b2[0];
        ws[5251] = 1.f / (1.f + expf(-z));
    }
    __syncthreads();
    // s1 table
    {
        int c = o;
        float t1 = 0.f;
        for (int oo = 0; oo < CCH; ++oo) {
            float acc = ws[5120 + oo] - ws[1024 + oo * CCH + c];
            t1 += fmaxf(acc, 0.f) * ws[5184 + oo];
        }
        float z = (t1 + ws[5250]) * ws[5248] + ws[5249];
        ws[5312 + c] = 1.f / (1.f + expf(-z));
    }
}

// s2 table: one block per c1, one thread per c2 (subtraction order matches
// the runtime fallback loop: base - w[c1] - w[c2], c1 < c2).
__global__ __launch_bounds__(64) void precomp2_kernel(float* __restrict__ ws)
{
    int c1 = blockIdx.x, c2 = threadIdx.x;
    float t = 0.f;
    for (int o = 0; o < CCH; ++o) {
        float acc = ws[5120 + o] - ws[1024 + o * CCH + c1] - ws[1024 + o * CCH + c2];
        t += fmaxf(acc, 0.f) * ws[5184 + o];
    }
    float z = (t + ws[5250]) * ws[5248] + ws[5249];
    ws[8192 + c1 * CCH + c2] = 1.f / (1.f + expf(-z));
}

// One block per (b,c) image: 256-bin histogram + first-max argmax.
__global__ __launch_bounds__(256) void hist_kernel(
    const float* __restrict__ x, int* __restrict__ dom)
{
    __shared__ unsigned h[16][NBINS + 1];
    __shared__ unsigned long long red[NBINS];
    int tid = threadIdx.x;
    const float4* xp = (const float4*)(x + (size_t)blockIdx.x * HWPIX);

    for (int i = tid; i < 16 * (NBINS + 1); i += 256) ((unsigned*)h)[i] = 0;
    __syncthreads();

    unsigned* hmine = h[tid >> 4];
    const float scale = 256.0f / 255.0f;
    #pragma unroll 4
    for (int t = 0; t < HWPIX / 4 / 256; ++t) {
        float4 v = xp[t * 256 + tid];
        float vv[4] = {v.x, v.y, v.z, v.w};
        #pragma unroll
        for (int j = 0; j < 4; ++j) {
            float f = vv[j];
            if (f >= 0.f && f <= 255.f) {
                int bi = (int)(f * scale);
                bi = bi > NBINS - 1 ? NBINS - 1 : bi;
                atomicAdd(&hmine[bi], 1u);
            }
        }
    }
    __syncthreads();

    unsigned cnt = 0;
    #pragma unroll
    for (int k = 0; k < 16; ++k) cnt += h[k][tid];
    red[tid] = ((unsigned long long)cnt << 32) | (unsigned)(NBINS - 1 - tid);
    __syncthreads();
    #pragma unroll
    for (int s = 128; s > 0; s >>= 1) {
        if (tid < s) {
            unsigned long long a = red[tid], b = red[tid + s];
            red[tid] = a > b ? a : b;
        }
        __syncthreads();
    }
    if (tid == 0) dom[blockIdx.x] = (NBINS - 1) - (int)(red[0] & 0xffffffffu);
}

// 64ch x 64px LDS tile, 8 blocks/CU. Per thread: 4 f4 loads + 4 f4 nt-stores.
__global__ __launch_bounds__(256, 8) void main_kernel(
    const float* __restrict__ x, const float* __restrict__ ws,
    const int* __restrict__ dom, float* __restrict__ out)
{
    __shared__ __align__(16) float tile[CCH][68];   // pad 68: conflict-free col reads, 16B rows
    __shared__ unsigned pm[4][CCH];
    __shared__ float ss[CCH];
    __shared__ float df[CCH];

    int tid = threadIdx.x;
    int b = blockIdx.x >> 10;            // 1024 blocks per batch image
    int p04 = (blockIdx.x & 1023) << 4;  // float4 offset of 64-px chunk

    if (tid < CCH) df[tid] = (float)dom[b * CCH + tid];

    const f4* xb4 = (const f4*)(x + ((size_t)b << 22));
    #pragma unroll
    for (int k = 0; k < 4; ++k) {
        int id = (k << 8) + tid;
        int c = id >> 4, col = id & 15;       // 16 float4 per channel row
        f4 v = xb4[((size_t)c << 14) + p04 + col];
        *(f4*)&tile[c][col << 2] = v;
    }
    __syncthreads();

    {   // each wave: 16 channels x 64 pixels
        int part = tid >> 6, px = tid & 63;
        unsigned mloc = 0;
        #pragma unroll
        for (int cc = 0; cc < 16; ++cc) {
            int c = (part << 4) | cc;
            float v = tile[c][px];
            float d = df[c];
            mloc |= (unsigned)(v >= d && v < d + 1.0f) << cc;
        }
        pm[part][px] = mloc;
    }
    __syncthreads();

    if (tid < CCH) {   // wave 0: combine partial masks, sigmoid per pixel
        int px = tid;
        unsigned long long m = (unsigned long long)pm[0][px]
            | ((unsigned long long)pm[1][px] << 16)
            | ((unsigned long long)pm[2][px] << 32)
            | ((unsigned long long)pm[3][px] << 48);
        float s;
        if (m == 0ull) {
            s = ws[5251];
        } else {
            int c1 = __builtin_ctzll(m);
            unsigned long long r1 = m & (m - 1);
            if (r1 == 0ull) {
                s = ws[5312 + c1];
            } else {
                int c2 = __builtin_ctzll(r1);
                unsigned long long r2 = r1 & (r1 - 1);
                if (r2 == 0ull) {
                    s = ws[8192 + (c1 << 6) + c2];
                } else {
                    float t = 0.f;
                    for (int o = 0; o < CCH; ++o) {
                        float acc = ws[5120 + o];
                        unsigned long long mm = m;
                        const float* row = ws + 1024 + (o << 6);
                        while (mm) {
                            int c = __builtin_ctzll(mm);
                            mm &= mm - 1;
                            acc -= row[c];
                        }
                        t += fmaxf(acc, 0.f) * ws[5184 + o];
                    }
                    float z = (t + ws[5250]) * ws[5248] + ws[5249];
                    s = 1.f / (1.f + expf(-z));
                }
            }
        }
        ss[px] = s;
    }
    __syncthreads();

    f4* ob4 = (f4*)(out + ((size_t)b << 22));
    #pragma unroll
    for (int k = 0; k < 4; ++k) {
        int id = (k << 8) + tid;
        int c = id >> 4, col = id & 15;
        f4 v = *(const f4*)&tile[c][col << 2];
        f4 sv = *(const f4*)&ss[col << 2];
        v *= sv;
        __builtin_nontemporal_store(v, &ob4[((size_t)c << 14) + p04 + col]);
    }
}

extern "C" void kernel_launch(void* const* d_in, const int* in_sizes, int n_in,
                              void* d_out, int out_size, void* d_ws, size_t ws_size,
                              hipStream_t stream) {
    const float* x   = (const float*)d_in[0];
    const float* w1  = (const float*)d_in[1];
    const float* b1  = (const float*)d_in[2];
    const float* g1  = (const float*)d_in[3];
    const float* be1 = (const float*)d_in[4];
    const float* m1  = (const float*)d_in[5];
    const float* v1  = (const float*)d_in[6];
    const float* w2  = (const float*)d_in[7];
    const float* b2  = (const float*)d_in[8];
    const float* g2  = (const float*)d_in[9];
    const float* be2 = (const float*)d_in[10];
    const float* m2  = (const float*)d_in[11];
    const float* v2  = (const float*)d_in[12];

    float* ws  = (float*)d_ws;
    int*   dom = (int*)d_ws;                 // aliases ws[0..1023]
    float* outp = (float*)d_out;

    int B = in_sizes[0] / (CCH * HWPIX);     // 16

    precomp_kernel<<<1, 64, 0, stream>>>(w1, b1, g1, be1, m1, v1,
                                         w2, b2, g2, be2, m2, v2, ws);
    precomp2_kernel<<<CCH, 64, 0, stream>>>(ws);
    hist_kernel<<<B * CCH, 256, 0, stream>>>(x, dom);
    main_kernel<<<B * (HWPIX / 64), 256, 0, stream>>>(x, ws, dom, outp);
}